// Round 2
// baseline (2285.896 us; speedup 1.0000x reference)
//
#include <hip/hip_runtime.h>
#include <stdint.h>

#define T_STEPS 200
#define OBSD    128
#define HID     128
#define LATD    32
#define BS_TOT  12800
#define KIN     160

#define OUT_ENT_OFF 81920000
#define OUT_LP_OFF  84480000

typedef short  bf16x8 __attribute__((ext_vector_type(8)));
typedef float  f32x4  __attribute__((ext_vector_type(4)));
typedef uint32_t u32;
typedef u32    u32x4  __attribute__((ext_vector_type(4)));

__device__ __forceinline__ uint16_t f2bf(float f) {
    u32 u = __builtin_bit_cast(u32, f);
    u32 r = (u + 0x7fffu + ((u >> 16) & 1u)) >> 16;
    return (uint16_t)r;
}
__device__ __forceinline__ float bf2f(u32 bits16) {
    u32 u = bits16 << 16;
    return __builtin_bit_cast(float, u);
}
__device__ __forceinline__ u32 pack2(float a, float b) {
    return (u32)f2bf(a) | ((u32)f2bf(b) << 16);
}
__device__ __forceinline__ u32 cvt_pk_bf16(float lo, float hi) {
    u32 r;
    asm("v_cvt_pk_bf16_f32 %0, %1, %2" : "=v"(r) : "v"(lo), "v"(hi));
    return r;
}
__device__ __forceinline__ float fast_sig(float x) {
    return __builtin_amdgcn_rcpf(1.f + __expf(-x));
}
__device__ __forceinline__ float fast_tanh(float x) {
    return 1.f - 2.f * __builtin_amdgcn_rcpf(1.f + __expf(2.f * x));
}

// ---------------------------------------------------------------------------
// Kernel 1: xg[t][bq][tid][8 uint4] = x @ W_ihx^T + b_ih + b_hh (bf16, in the
// main kernel's fragment order). Unchanged from the passing round-1 version.
// ---------------------------------------------------------------------------
__global__ __launch_bounds__(512, 2) void xg_prep(
    const float* __restrict__ x,
    const float* __restrict__ W_ih,
    const float* __restrict__ b_ih,
    const float* __restrict__ b_hh,
    uint16_t* __restrict__ xg)
{
    const int blk = blockIdx.x;
    const int t   = blk >> 2, bq = blk & 3;
    const int tid = threadIdx.x;
    const int w = tid >> 6, l = tid & 63, lg = l >> 4, ln = l & 15;
    const int b0 = bq * 64;

    bf16x8 wb[4][4];
    float  bias[4];
    #pragma unroll
    for (int q = 0; q < 4; ++q) {
        const int col = q * 128 + w * 16 + ln;
        bias[q] = b_ih[col] + b_hh[col];
        #pragma unroll
        for (int ks = 0; ks < 4; ++ks) {
            bf16x8 v;
            #pragma unroll
            for (int e = 0; e < 8; ++e)
                v[e] = (short)f2bf(W_ih[col * KIN + ks * 32 + lg * 8 + e]);
            wb[ks][q] = v;
        }
    }

    f32x4 acc[4][4];
    const f32x4 vz = {0.f, 0.f, 0.f, 0.f};
    #pragma unroll
    for (int rt = 0; rt < 4; ++rt)
        #pragma unroll
        for (int q = 0; q < 4; ++q) acc[rt][q] = vz;

    #pragma unroll
    for (int ks = 0; ks < 4; ++ks) {
        bf16x8 a[4];
        #pragma unroll
        for (int rt = 0; rt < 4; ++rt) {
            const int brow = b0 + rt * 16 + ln;
            const float* src = x + ((size_t)brow * T_STEPS + t) * OBSD + ks * 32 + lg * 8;
            bf16x8 v;
            #pragma unroll
            for (int e = 0; e < 8; ++e) v[e] = (short)f2bf(src[e]);
            a[rt] = v;
        }
        #pragma unroll
        for (int rt = 0; rt < 4; ++rt)
            #pragma unroll
            for (int q = 0; q < 4; ++q)
                acc[rt][q] = __builtin_amdgcn_mfma_f32_16x16x32_bf16(
                    a[rt], wb[ks][q], acc[rt][q], 0, 0, 0);
    }

    uint4* dst = (uint4*)xg + ((size_t)blk * 512 + tid) * 8;
    #pragma unroll
    for (int rt = 0; rt < 4; ++rt) {
        float v0[4], v1[4], v2[4], v3[4];
        #pragma unroll
        for (int e = 0; e < 4; ++e) {
            v0[e] = acc[rt][0][e] + bias[0];
            v1[e] = acc[rt][1][e] + bias[1];
            v2[e] = acc[rt][2][e] + bias[2];
            v3[e] = acc[rt][3][e] + bias[3];
        }
        uint4 o0, o1;
        o0.x = pack2(v0[0], v0[1]); o0.y = pack2(v0[2], v0[3]);
        o0.z = pack2(v1[0], v1[1]); o0.w = pack2(v1[2], v1[3]);
        o1.x = pack2(v2[0], v2[1]); o1.y = pack2(v2[2], v2[3]);
        o1.z = pack2(v3[0], v3[1]); o1.w = pack2(v3[2], v3[3]);
        dst[2 * rt]     = o0;
        dst[2 * rt + 1] = o1;
    }
}

// ---------------------------------------------------------------------------
// Kernel 2: entropies = constant
// ---------------------------------------------------------------------------
__global__ void ent_fill(const float* __restrict__ cov, float* __restrict__ out)
{
    __shared__ float ec;
    if (threadIdx.x == 0) {
        float logdet = 0.f;
        for (int i = 0; i < LATD; ++i) logdet += logf(cov[i]);
        ec = 0.5f * 32.f * (1.f + 1.8378770664093453f) + 0.5f * logdet;
    }
    __syncthreads();
    const int idx = blockIdx.x * blockDim.x + threadIdx.x;
    const int stride = gridDim.x * blockDim.x;
    for (int i = idx; i < 2560000; i += stride)
        out[OUT_ENT_OFF + i] = ec;
}

// ---------------------------------------------------------------------------
// Kernel 3: recurrence with z folded out of the critical path.
//   Wr = W_hh + W_ihz @ W_mu  (computed per-block at init, K=128)
//   gates_t = xg_t + zbias + (eps_{t-1}*std) @ W_ihz^T + h_{t-1} @ Wr^T
//   z_{t-1} = h_{t-1} @ W_mu^T + b_mu + eps_{t-1}*std   (overlapped, off-path)
// 2 barriers/step. LDS: h[64][136] bf16 + eps stage [64][36] f32.
// ---------------------------------------------------------------------------
__global__ __launch_bounds__(512, 2) void lstm_main(
    const float* __restrict__ eps,
    const float* __restrict__ W_ih,
    const float* __restrict__ W_hh,
    const float* __restrict__ W_mu,
    const float* __restrict__ b_mu,
    const float* __restrict__ cov,
    const uint16_t* __restrict__ xg,
    float* __restrict__ out)
{
    __shared__ __align__(16) char smem[64 * 136 * 2 + 64 * 36 * 4];
    uint16_t* h_lds = (uint16_t*)smem;
    float*    e_lds = (float*)(smem + 64 * 136 * 2);
    float*    wmu_s = (float*)smem;            // init-time alias (16 KB)

    const int blk = blockIdx.x, bq = blk & 3;
    const int bs0 = blk * 64;
    const int tid = threadIdx.x;
    const int w = tid >> 6, l = tid & 63, lg = l >> 4, ln = l & 15;

    // stage W_mu (4096 f32) into LDS for broadcast reads during Wr build
    for (int i = tid; i < 4096; i += 512) wmu_s[i] = W_mu[i];
    __syncthreads();

    // ---- build weight fragments ----
    bf16x8 wr[4][4];   // Wr combined, [ks][q]
    bf16x8 weg[4];     // W_ihz fragments (K=32)
    float  zbias[4];
    #pragma unroll
    for (int q = 0; q < 4; ++q) {
        const int col = q * 128 + w * 16 + ln;
        float wzf[32];
        #pragma unroll
        for (int j4 = 0; j4 < 8; ++j4)
            *(float4*)&wzf[j4 * 4] = *(const float4*)&W_ih[col * KIN + 128 + j4 * 4];
        float zb = 0.f;
        #pragma unroll
        for (int j = 0; j < 32; ++j) zb += b_mu[j] * wzf[j];
        zbias[q] = zb;
        {
            bf16x8 v;
            #pragma unroll
            for (int e = 0; e < 8; ++e) v[e] = (short)f2bf(wzf[lg * 8 + e]);
            weg[q] = v;
        }
        #pragma unroll
        for (int ks = 0; ks < 4; ++ks) {
            float base[8];
            *(float4*)&base[0] = *(const float4*)&W_hh[col * HID + ks * 32 + lg * 8];
            *(float4*)&base[4] = *(const float4*)&W_hh[col * HID + ks * 32 + lg * 8 + 4];
            bf16x8 v;
            #pragma unroll
            for (int e = 0; e < 8; ++e) {
                float s = base[e];
                #pragma unroll
                for (int j = 0; j < 32; ++j)
                    s += wzf[j] * wmu_s[j * HID + ks * 32 + lg * 8 + e];
                v[e] = (short)f2bf(s);
            }
            wr[ks][q] = v;
        }
    }

    // mean-phase constants (wave w -> output tile rtm, ctm)
    const int rtm = w >> 1, ctm = w & 1;
    const int zcol = ctm * 16 + ln;
    bf16x8 wmu[4];
    #pragma unroll
    for (int ks = 0; ks < 4; ++ks) {
        bf16x8 v;
        #pragma unroll
        for (int e = 0; e < 8; ++e)
            v[e] = (short)f2bf(wmu_s[zcol * HID + ks * 32 + lg * 8 + e]);
        wmu[ks] = v;
    }
    const float stdv = sqrtf(cov[zcol]);
    const float bmu  = b_mu[zcol];
    float stdv8[8];
    #pragma unroll
    for (int e = 0; e < 8; ++e) stdv8[e] = sqrtf(cov[lg * 8 + e]);
    float logdet = 0.f;
    for (int i = 0; i < LATD; ++i) logdet += logf(cov[i]);
    const float lconst = 32.f * 1.8378770664093453f + logdet;

    const f32x4 vz4 = {0.f, 0.f, 0.f, 0.f};
    f32x4 cst[4];
    #pragma unroll
    for (int rt = 0; rt < 4; ++rt) cst[rt] = vz4;
    u32x4 epf[4];          // scaled eps_{t} bf16 A-fragments (for step t+1)
    float ev[4];           // eps_t at (mean rows, zcol) for z_t

    const int sr = tid >> 3, sc = (tid & 7) * 4;   // eps staging map

    for (int t = 0; t < T_STEPS; ++t) {
        // issue global loads early (consumed after phase A / after barA)
        uint4 xv[8];
        const uint4* xp = (const uint4*)xg + ((size_t)(t * 4 + bq) * 512 + tid) * 8;
        #pragma unroll
        for (int i = 0; i < 8; ++i) xv[i] = xp[i];
        const float4 ev4 = *(const float4*)(eps + ((size_t)t * BS_TOT + bs0 + sr) * LATD + sc);

        f32x4 acc[4][4];
        #pragma unroll
        for (int rt = 0; rt < 4; ++rt)
            #pragma unroll
            for (int q = 0; q < 4; ++q) acc[rt][q] = vz4;

        if (t > 0) {
            // eg: (eps_{t-1} * std) @ W_ihz^T, K=32
            #pragma unroll
            for (int rt = 0; rt < 4; ++rt) {
                const bf16x8 a = __builtin_bit_cast(bf16x8, epf[rt]);
                #pragma unroll
                for (int q = 0; q < 4; ++q)
                    acc[rt][q] = __builtin_amdgcn_mfma_f32_16x16x32_bf16(
                        a, weg[q], acc[rt][q], 0, 0, 0);
            }
            // gates: h_{t-1} @ Wr^T, K=128
            #pragma unroll
            for (int ks = 0; ks < 4; ++ks) {
                bf16x8 a[4];
                #pragma unroll
                for (int rt = 0; rt < 4; ++rt)
                    a[rt] = *(const bf16x8*)&h_lds[(rt * 16 + ln) * 136 + ks * 32 + lg * 8];
                #pragma unroll
                for (int rt = 0; rt < 4; ++rt)
                    #pragma unroll
                    for (int q = 0; q < 4; ++q)
                        acc[rt][q] = __builtin_amdgcn_mfma_f32_16x16x32_bf16(
                            a[rt], wr[ks][q], acc[rt][q], 0, 0, 0);
            }
            // mean for step t-1 (reads h_{t-1}, off critical path)
            f32x4 macc = vz4;
            #pragma unroll
            for (int ks = 0; ks < 4; ++ks) {
                const bf16x8 am = *(const bf16x8*)&h_lds[(rtm * 16 + ln) * 136 + ks * 32 + lg * 8];
                macc = __builtin_amdgcn_mfma_f32_16x16x32_bf16(am, wmu[ks], macc, 0, 0, 0);
            }
            #pragma unroll
            for (int e = 0; e < 4; ++e) {
                const int row = rtm * 16 + lg * 4 + e;
                out[(size_t)(bs0 + row) * 6400 + (t - 1) * 32 + zcol] =
                    macc[e] + bmu + ev[e] * stdv;
            }
        }

        // stage eps_t into LDS (write after compute so vmcnt wait overlaps MFMAs)
        *(float4*)&e_lds[sr * 36 + sc] = ev4;
        __syncthreads();   // barA: h_{t-1} reads done; eps_t staged

        // ---- LSTM elementwise ----
        const float zi = (t > 0) ? zbias[0] : 0.f;
        const float zf = (t > 0) ? zbias[1] : 0.f;
        const float zg = (t > 0) ? zbias[2] : 0.f;
        const float zo = (t > 0) ? zbias[3] : 0.f;
        #pragma unroll
        for (int rt = 0; rt < 4; ++rt) {
            const uint4 u01 = xv[2 * rt], u23 = xv[2 * rt + 1];
            const float xi[4] = { bf2f(u01.x & 0xffff), bf2f(u01.x >> 16),
                                  bf2f(u01.y & 0xffff), bf2f(u01.y >> 16) };
            const float xf[4] = { bf2f(u01.z & 0xffff), bf2f(u01.z >> 16),
                                  bf2f(u01.w & 0xffff), bf2f(u01.w >> 16) };
            const float xgv[4] = { bf2f(u23.x & 0xffff), bf2f(u23.x >> 16),
                                   bf2f(u23.y & 0xffff), bf2f(u23.y >> 16) };
            const float xo[4] = { bf2f(u23.z & 0xffff), bf2f(u23.z >> 16),
                                  bf2f(u23.w & 0xffff), bf2f(u23.w >> 16) };
            float hv[4];
            #pragma unroll
            for (int e = 0; e < 4; ++e) {
                const float iv = acc[rt][0][e] + xi[e]  + zi;
                const float fv = acc[rt][1][e] + xf[e]  + zf;
                const float gv = acc[rt][2][e] + xgv[e] + zg;
                const float ov = acc[rt][3][e] + xo[e]  + zo;
                const float c  = fast_sig(fv) * cst[rt][e] + fast_sig(iv) * fast_tanh(gv);
                cst[rt][e] = c;
                hv[e] = fast_sig(ov) * fast_tanh(c);
            }
            const u32 p01 = cvt_pk_bf16(hv[0], hv[1]);
            const u32 p23 = cvt_pk_bf16(hv[2], hv[3]);
            const int rb = (rt * 16 + lg * 4) * 136 + w * 16 + ln;
            h_lds[rb]       = (uint16_t)p01;
            h_lds[rb + 136] = (uint16_t)(p01 >> 16);
            h_lds[rb + 272] = (uint16_t)p23;
            h_lds[rb + 408] = (uint16_t)(p23 >> 16);
        }

        // ---- eps_t prep for next step + log-prob(t) ----
        float ps4[4];
        #pragma unroll
        for (int rt = 0; rt < 4; ++rt) {
            const float* ep = &e_lds[(rt * 16 + ln) * 36 + lg * 8];
            float er[8];
            *(float4*)&er[0] = *(const float4*)&ep[0];
            *(float4*)&er[4] = *(const float4*)&ep[4];
            float ps = 0.f;
            #pragma unroll
            for (int i = 0; i < 8; ++i) ps += er[i] * er[i];
            ps4[rt] = ps;
            u32x4 pk;
            pk[0] = cvt_pk_bf16(er[0] * stdv8[0], er[1] * stdv8[1]);
            pk[1] = cvt_pk_bf16(er[2] * stdv8[2], er[3] * stdv8[3]);
            pk[2] = cvt_pk_bf16(er[4] * stdv8[4], er[5] * stdv8[5]);
            pk[3] = cvt_pk_bf16(er[6] * stdv8[6], er[7] * stdv8[7]);
            epf[rt] = pk;
        }
        #pragma unroll
        for (int rt = 0; rt < 4; ++rt) {
            ps4[rt] += __shfl_xor(ps4[rt], 16, 64);
            ps4[rt] += __shfl_xor(ps4[rt], 32, 64);
        }
        if (w == 0 && lg == 0) {
            #pragma unroll
            for (int rt = 0; rt < 4; ++rt)
                out[OUT_LP_OFF + (size_t)(bs0 + rt * 16 + ln) * 200 + t] =
                    -0.5f * (ps4[rt] + lconst);
        }
        // eps_t at (mean rows, zcol) for z_t next iteration
        #pragma unroll
        for (int e = 0; e < 4; ++e)
            ev[e] = e_lds[(rtm * 16 + lg * 4 + e) * 36 + zcol];

        __syncthreads();   // barB: h_t visible; e_lds reads done
    }

    // epilogue: z for t = 199
    {
        f32x4 macc = vz4;
        #pragma unroll
        for (int ks = 0; ks < 4; ++ks) {
            const bf16x8 am = *(const bf16x8*)&h_lds[(rtm * 16 + ln) * 136 + ks * 32 + lg * 8];
            macc = __builtin_amdgcn_mfma_f32_16x16x32_bf16(am, wmu[ks], macc, 0, 0, 0);
        }
        #pragma unroll
        for (int e = 0; e < 4; ++e) {
            const int row = rtm * 16 + lg * 4 + e;
            out[(size_t)(bs0 + row) * 6400 + 199 * 32 + zcol] =
                macc[e] + bmu + ev[e] * stdv;
        }
    }
}

extern "C" void kernel_launch(void* const* d_in, const int* in_sizes, int n_in,
                              void* d_out, int out_size, void* d_ws, size_t ws_size,
                              hipStream_t stream) {
    const float* x    = (const float*)d_in[0];
    const float* eps  = (const float*)d_in[1];
    const float* W_ih = (const float*)d_in[2];
    const float* W_hh = (const float*)d_in[3];
    const float* b_ih = (const float*)d_in[4];
    const float* b_hh = (const float*)d_in[5];
    const float* W_mu = (const float*)d_in[6];
    const float* b_mu = (const float*)d_in[7];
    const float* cov  = (const float*)d_in[8];
    float* out = (float*)d_out;
    uint16_t* xg = (uint16_t*)d_ws;   // 52,428,800 bytes

    hipLaunchKernelGGL(xg_prep, dim3(800), dim3(512), 0, stream, x, W_ih, b_ih, b_hh, xg);
    hipLaunchKernelGGL(ent_fill, dim3(2048), dim3(256), 0, stream, cov, out);
    hipLaunchKernelGGL(lstm_main, dim3(200), dim3(512), 0, stream,
                       eps, W_ih, W_hh, W_mu, b_mu, cov, xg, out);
}